// Round 1
// baseline (275.009 us; speedup 1.0000x reference)
//
#include <hip/hip_runtime.h>

#define NPTS 65536          // B*N = 32*2048
#define HH 256
#define DIN 131
#define LAT 128
#define STEPS 5
#define DT 0.2f
#define P 32                // points per block
#define PADK 264            // padded row length (bf16 elems)

typedef unsigned int uint;
typedef unsigned short ushort;
typedef __attribute__((ext_vector_type(8))) short short8;
typedef __attribute__((ext_vector_type(4))) float floatx4;

__device__ __forceinline__ float tanh_fast(float x) {
    // tanh(x) = 1 - 2/(exp2(2x*log2e)+1); exact at both saturated ends.
    float e = __builtin_amdgcn_exp2f(x * 2.8853900817779268f);
    return 1.0f - 2.0f * __builtin_amdgcn_rcpf(e + 1.0f);
}

__device__ __forceinline__ ushort f2bf(float f) {
    uint u = __builtin_bit_cast(uint, f);
    u += 0x7fffu + ((u >> 16) & 1u);   // RNE
    return (ushort)(u >> 16);
}

// ---- prep: a1[b][h] = b1[h] + sum_l z[b][l]*W1[h][3+l]; rs[h] = sum_l W1[h][3+l];
// ---- wsw = W2 as bf16 B-fragments: wsw[((nt*8+kt)*64+lane)*8+j] = W2[nt*16+(lane&15)][kt*32+(lane>>4)*8+j]
__global__ void prep_kernel(const float* __restrict__ z, const float* __restrict__ W1,
                            const float* __restrict__ b1, const float* __restrict__ W2,
                            float* __restrict__ a1, float* __restrict__ rsv,
                            ushort* __restrict__ wsw)
{
    int tid = blockIdx.x * 256 + threadIdx.x;
    if (tid < 8192) {
        int b = tid >> 8, h = tid & 255;
        const float* wrow = W1 + h * DIN + 3;
        const float* zb = z + b * LAT;
        float s = b1[h], r = 0.f;
        for (int l = 0; l < LAT; ++l) { float wv = wrow[l]; s += wv * zb[l]; r += wv; }
        a1[tid] = s;
        if (b == 0) rsv[h] = r;
    } else {
        int t = tid - 8192;                    // 0..8191
        int lane = t & 63, kt = (t >> 6) & 7, nt = t >> 9;
        int n = nt * 16 + (lane & 15);
        int k = kt * 32 + (lane >> 4) * 8;
        const float* src = W2 + n * HH + k;
        ushort* dst = wsw + t * 8;
        #pragma unroll
        for (int j = 0; j < 8; ++j) dst[j] = f2bf(src[j]);
    }
}

__global__ __launch_bounds__(256, 2) void cnf_kernel(
        const float* __restrict__ xin, const float* __restrict__ W1,
        const float* __restrict__ b2, const float* __restrict__ W3,
        const float* __restrict__ b3, const float* __restrict__ osc,
        const float* __restrict__ a1, const float* __restrict__ rsv,
        const ushort* __restrict__ wsw, float* __restrict__ out)
{
    __shared__ __align__(16) ushort V[3][P][PADK];   // V0=h1, V1=g1*W1x0, V2=g1*W1x1 (bf16)
    __shared__ float a1s[HH], rsS[HH], wx0s[HH], wx1s[HH], wts[HH];
    __shared__ float X0[P], X1[P], C[P];
    __shared__ float sums[4][P][3];                  // per-wave partial [v0,v1,div]

    const int tid = threadIdx.x;
    const int lane = tid & 63;
    const int w = tid >> 6;
    const int r15 = lane & 15;
    const int q = lane >> 4;
    const int blk = blockIdx.x;
    const int b = blk >> 6;                          // 64 blocks per batch
    const int pbase = blk * P;

    if (tid < HH) {
        a1s[tid] = a1[b * HH + tid];
        rsS[tid] = rsv[tid];
        wx0s[tid] = W1[tid * DIN + 0];
        wx1s[tid] = W1[tid * DIN + 1];
        wts[tid]  = W1[tid * DIN + 2];
    }
    if (tid < P) {
        int gp = pbase + tid;
        X0[tid] = xin[gp * 2 + 0];
        X1[tid] = xin[gp * 2 + 1];
        C[tid] = 0.f;                                // log_det == ctx-accumulator
    }
    const float os = osc[0];
    const float b30 = b3[0], b31 = b3[1];
    float w30r[4], w31r[4], b2r[4];
    #pragma unroll
    for (int n = 0; n < 4; ++n) {
        int j = (w * 4 + n) * 16 + r15;              // this lane's output column
        w30r[n] = W3[j];
        w31r[n] = W3[HH + j];
        b2r[n] = b2[j];
    }
    __syncthreads();

    const int hp = tid & 127;
    const int h0 = hp * 2;
    const int pst = tid >> 7;

    for (int s = 0; s < STEPS; ++s) {
        const float tcur = (float)s * DT;

        // ---- phase 1: layer-1 (collapsed) + build bf16 A-matrices in LDS ----
        {
            float wa = wx0s[h0], wb = wx0s[h0 + 1];
            float wc = wx1s[h0], wd = wx1s[h0 + 1];
            float ra = rsS[h0],  rb = rsS[h0 + 1];
            float ba = a1s[h0]     + wts[h0]     * tcur;
            float bbv = a1s[h0 + 1] + wts[h0 + 1] * tcur;
            #pragma unroll
            for (int i = 0; i < 16; ++i) {
                int p = pst + 2 * i;
                float x0 = X0[p], x1 = X1[p], cc = C[p];
                float pa = ba  + wa * x0 + wc * x1 + ra * cc;
                float pb = bbv + wb * x0 + wd * x1 + rb * cc;
                float ha = tanh_fast(pa), hb = tanh_fast(pb);
                float ga = 1.f - ha * ha, gb = 1.f - hb * hb;
                *(uint*)&V[0][p][h0] = (uint)f2bf(ha)      | ((uint)f2bf(hb)      << 16);
                *(uint*)&V[1][p][h0] = (uint)f2bf(ga * wa) | ((uint)f2bf(gb * wb) << 16);
                *(uint*)&V[2][p][h0] = (uint)f2bf(ga * wc) | ((uint)f2bf(gb * wd) << 16);
            }
        }
        __syncthreads();

        // ---- GEMM: R[v] = V[v] @ W2^T via mfma_f32_16x16x32_bf16 ----
        floatx4 acc[3][2][4];
        #pragma unroll
        for (int v = 0; v < 3; ++v)
            #pragma unroll
            for (int mt = 0; mt < 2; ++mt)
                #pragma unroll
                for (int n = 0; n < 4; ++n)
                    acc[v][mt][n] = (floatx4){0.f, 0.f, 0.f, 0.f};

        const ushort* wb_ = wsw + (size_t)(w * 4) * 4096 + (size_t)lane * 8;
        #pragma unroll
        for (int kt = 0; kt < 8; ++kt) {
            const int koff = kt * 32 + q * 8;
            short8 af[3][2];
            #pragma unroll
            for (int v = 0; v < 3; ++v)
                #pragma unroll
                for (int mt = 0; mt < 2; ++mt)
                    af[v][mt] = *(const short8*)&V[v][mt * 16 + r15][koff];
            #pragma unroll
            for (int n = 0; n < 4; ++n) {
                short8 bfr = *(const short8*)(wb_ + (size_t)(n * 8 + kt) * 512);
                #pragma unroll
                for (int mt = 0; mt < 2; ++mt)
                    #pragma unroll
                    for (int v = 0; v < 3; ++v)
                        acc[v][mt][n] = __builtin_amdgcn_mfma_f32_16x16x32_bf16(
                            af[v][mt], bfr, acc[v][mt][n], 0, 0, 0);
            }
        }

        // ---- epilogue: h2/g2, project with W3, reduce j, stash per-wave sums ----
        #pragma unroll
        for (int mt = 0; mt < 2; ++mt) {
            float sv0[4] = {0,0,0,0}, sv1[4] = {0,0,0,0}, sdv[4] = {0,0,0,0};
            #pragma unroll
            for (int n = 0; n < 4; ++n) {
                float w0 = w30r[n], w1 = w31r[n], bbj = b2r[n];
                #pragma unroll
                for (int r = 0; r < 4; ++r) {
                    float h2 = tanh_fast(acc[0][mt][n][r] + bbj);
                    float g2 = 1.f - h2 * h2;
                    sv0[r] += h2 * w0;
                    sv1[r] += h2 * w1;
                    sdv[r] += g2 * (acc[1][mt][n][r] * w0 + acc[2][mt][n][r] * w1);
                }
            }
            #pragma unroll
            for (int r = 0; r < 4; ++r) {
                float ta = sv0[r], tb = sv1[r], td = sdv[r];
                #pragma unroll
                for (int off = 1; off < 16; off <<= 1) {
                    ta += __shfl_xor(ta, off);
                    tb += __shfl_xor(tb, off);
                    td += __shfl_xor(td, off);
                }
                if (r15 == 0) {
                    int p = mt * 16 + q * 4 + r;
                    sums[w][p][0] = ta;
                    sums[w][p][1] = tb;
                    sums[w][p][2] = td;
                }
            }
        }
        __syncthreads();

        // ---- state update (Euler) ----
        if (tid < P) {
            float s0 = sums[0][tid][0] + sums[1][tid][0] + sums[2][tid][0] + sums[3][tid][0];
            float s1 = sums[0][tid][1] + sums[1][tid][1] + sums[2][tid][1] + sums[3][tid][1];
            float sd = sums[0][tid][2] + sums[1][tid][2] + sums[2][tid][2] + sums[3][tid][2];
            X0[tid] += (s0 + b30) * os * DT;
            X1[tid] += (s1 + b31) * os * DT;
            C[tid]  += sd * os * DT;
        }
        __syncthreads();
    }

    if (tid < P) {
        int gp = pbase + tid;
        out[gp * 2 + 0] = X0[tid];
        out[gp * 2 + 1] = X1[tid];
        out[NPTS * 2 + gp] = C[tid];      // log_det == C
    }
}

extern "C" void kernel_launch(void* const* d_in, const int* in_sizes, int n_in,
                              void* d_out, int out_size, void* d_ws, size_t ws_size,
                              hipStream_t stream) {
    const float* x   = (const float*)d_in[0];
    const float* z   = (const float*)d_in[1];
    const float* W1  = (const float*)d_in[2];
    const float* b1  = (const float*)d_in[3];
    const float* W2  = (const float*)d_in[4];
    const float* b2  = (const float*)d_in[5];
    const float* W3  = (const float*)d_in[6];
    const float* b3  = (const float*)d_in[7];
    const float* osc = (const float*)d_in[8];

    // ws layout: a1 [8192 f] @0 | rs [256 f] @32768B | wsw [65536 bf16] @33792B  (~165KB)
    float* a1  = (float*)d_ws;
    float* rsv = a1 + 8192;
    ushort* wsw = (ushort*)((char*)d_ws + 33792);

    hipLaunchKernelGGL(prep_kernel, dim3(64), dim3(256), 0, stream, z, W1, b1, W2, a1, rsv, wsw);
    hipLaunchKernelGGL(cnf_kernel, dim3(2048), dim3(256), 0, stream,
                       x, W1, b2, W3, b3, osc, a1, rsv, wsw, (float*)d_out);
}